// Round 1
// baseline (114.150 us; speedup 1.0000x reference)
//
#include <hip/hip_runtime.h>

#define XD 192
#define YD 192
#define CCH 3
#define RFK 24
#define IMG 224

// ---- ws layout (float offsets) ----
#define OFF_AFF 0
#define N_AFF (XD*YD)                   // 36864
#define OFF_PAD (OFF_AFF + N_AFF)       // 36864
#define PADW 320                        // act row padded: col = y + 64, cols 0..319
#define N_PAD (CCH*XD*PADW)             // 184320
#define OFF_KI (OFF_PAD + N_PAD)        // 221184 (16B aligned)
#define KI_LD 96                        // 94 cols + 2 zero pad
#define N_KI (94*KI_LD)                 // 9024
#define OFF_KE (OFF_KI + N_KI)          // 230208 (16B aligned)
#define KE_LD 40                        // 38 cols + 2 zero pad
#define N_KE (38*KE_LD)                 // 1520

#define AFF_BLOCKS 9216                 // 4 waves/block, 1 wave per (x,y)
#define PREP_BLOCKS 192
#define QSPLIT 8

// Kernel 1: afferent dot-products (one wave per output pixel) + prep blocks
// that build the padded activation and the masked, gamma-prescaled lateral
// kernels in workspace.
__global__ __launch_bounds__(256) void k_aff_prep(
    const float* __restrict__ input, const float* __restrict__ affw,
    const float* __restrict__ affm, const float* __restrict__ exw,
    const float* __restrict__ exm,  const float* __restrict__ inw,
    const float* __restrict__ inm,  const float* __restrict__ oldact,
    const int*   __restrict__ rfstart, float* __restrict__ ws)
{
    const int bid = blockIdx.x;
    const int tid = threadIdx.x;

    if (bid < AFF_BLOCKS) {
        const int xy   = bid * 4 + (tid >> 6);   // 0..36863
        const int lane = tid & 63;
        const int sx = rfstart[xy * 2 + 0];
        const int sy = rfstart[xy * 2 + 1];
        const float4* W4 = (const float4*)affw;  // [(c*36864+xy)*144 + r]
        const float4* M4 = (const float4*)affm;  // [r], r in [0,144)
        float acc = 0.f;
        // 432 vec4 groups: c = g/144, r = g%144, u = r/6, v = 4*(r%6)
        for (int g = lane; g < 432; g += 64) {
            const int c = (g >= 288) ? 2 : ((g >= 144) ? 1 : 0);
            const int r = g - c * 144;
            const float4 w4 = W4[(size_t)(c * 36864 + xy) * 144 + r];
            const float4 m4 = M4[r];
            const int u = (r * 2731) >> 14;        // r/6 for r<144
            const int v = (r - u * 6) * 4;
            const float* ip = input + c * (IMG * IMG) + (sx + u) * IMG + (sy + v);
            acc += ip[0] * m4.x * w4.x;
            acc += ip[1] * m4.y * w4.y;
            acc += ip[2] * m4.z * w4.z;
            acc += ip[3] * m4.w * w4.w;
        }
        #pragma unroll
        for (int off = 32; off > 0; off >>= 1) acc += __shfl_xor(acc, off);
        if (lane == 0) ws[OFF_AFF + xy] = acc;
    } else {
        // prep: padded activation + masked prescaled kernels
        const int p = (bid - AFF_BLOCKS) * 256 + tid;
        const int TOT = N_PAD + N_KI + N_KE;
        for (int idx = p; idx < TOT; idx += PREP_BLOCKS * 256) {
            if (idx < N_PAD) {
                const int col = idx % PADW;
                const int rem = idx / PADW;
                const int xx = rem % XD;
                const int cc = rem / XD;
                float v = 0.f;
                if (col >= 64 && col < 64 + YD)
                    v = oldact[(cc * XD + xx) * YD + (col - 64)];
                ws[OFF_PAD + idx] = v;
            } else if (idx < N_PAD + N_KI) {
                const int k = idx - N_PAD;
                const int i = k / KI_LD, j = k % KI_LD;
                ws[OFF_KI + k] = (j < 94) ? (-0.9f * inw[i * 94 + j] * inm[i * 94 + j]) : 0.f;
            } else {
                const int k = idx - N_PAD - N_KI;
                const int i = k / KE_LD, j = k % KE_LD;
                ws[OFF_KE + k] = (j < 38) ? (0.9f * exw[i * 38 + j] * exm[i * 38 + j]) : 0.f;
            }
        }
    }
}

// Kernel 2: lateral convolutions via register sliding window.
// Block = 256 threads: yg = tid&31 (6 y-outputs each, 32*6=192), xr = tid>>5
// (8 x-rows). Grid (24 x-tiles, 3 channels, QSPLIT kernel-row phases).
// Accumulated with atomicAdd into zeroed out; q==0 also adds afferent.
__global__ __launch_bounds__(256) void k_lateral(
    const float* __restrict__ ws, float* __restrict__ out)
{
    const int xt = blockIdx.x;   // 0..23
    const int c  = blockIdx.y;   // 0..2
    const int q  = blockIdx.z;   // 0..QSPLIT-1
    const int tid = threadIdx.x;
    const int yg = tid & 31;
    const int xr = tid >> 5;
    const int x  = xt * 8 + xr;
    const int y0 = yg * 6;

    float acc[6] = {0.f, 0.f, 0.f, 0.f, 0.f, 0.f};
    const float* pad = ws + OFF_PAD + (size_t)c * XD * PADW;

    // inhibitory 94x94 (weights pre-scaled by -0.9), act col = y + j - 47 + 64
    for (int i = q; i < 94; i += QSPLIT) {
        const int r = x + i - 47;
        if (r < 0 || r >= XD) continue;
        const float* row = pad + r * PADW + y0 + 17;
        const float4* kw = (const float4*)(ws + OFF_KI + i * KI_LD);
        float w[9];
        #pragma unroll
        for (int k = 0; k < 9; ++k) w[k] = row[k];
        #pragma unroll
        for (int g = 0; g < 24; ++g) {
            const float4 k4 = kw[g];
            #pragma unroll
            for (int t = 0; t < 6; ++t) {
                acc[t] += k4.x * w[0 + t];
                acc[t] += k4.y * w[1 + t];
                acc[t] += k4.z * w[2 + t];
                acc[t] += k4.w * w[3 + t];
            }
            #pragma unroll
            for (int k = 0; k < 5; ++k) w[k] = w[k + 4];
            #pragma unroll
            for (int k = 5; k < 9; ++k) w[k] = row[4 * (g + 1) + k];
        }
    }

    // excitatory 38x38 (weights pre-scaled by +0.9), act col = y + j - 19 + 64
    for (int i = q; i < 38; i += QSPLIT) {
        const int r = x + i - 19;
        if (r < 0 || r >= XD) continue;
        const float* row = pad + r * PADW + y0 + 45;
        const float4* kw = (const float4*)(ws + OFF_KE + i * KE_LD);
        float w[9];
        #pragma unroll
        for (int k = 0; k < 9; ++k) w[k] = row[k];
        #pragma unroll
        for (int g = 0; g < 10; ++g) {
            const float4 k4 = kw[g];
            #pragma unroll
            for (int t = 0; t < 6; ++t) {
                acc[t] += k4.x * w[0 + t];
                acc[t] += k4.y * w[1 + t];
                acc[t] += k4.z * w[2 + t];
                acc[t] += k4.w * w[3 + t];
            }
            #pragma unroll
            for (int k = 0; k < 5; ++k) w[k] = w[k + 4];
            #pragma unroll
            for (int k = 5; k < 9; ++k) w[k] = row[4 * (g + 1) + k];
        }
    }

    if (q == 0) {
        const float* aff = ws + OFF_AFF + x * YD + y0;
        #pragma unroll
        for (int t = 0; t < 6; ++t) acc[t] += aff[t];
    }

    float* op = out + (size_t)(c * XD + x) * YD + y0;
    #pragma unroll
    for (int t = 0; t < 6; ++t) atomicAdd(&op[t], acc[t]);
}

extern "C" void kernel_launch(void* const* d_in, const int* in_sizes, int n_in,
                              void* d_out, int out_size, void* d_ws, size_t ws_size,
                              hipStream_t stream)
{
    const float* input   = (const float*)d_in[0];
    const float* affw    = (const float*)d_in[1];
    const float* exw     = (const float*)d_in[2];
    const float* inw     = (const float*)d_in[3];
    const float* affm    = (const float*)d_in[4];
    const float* exm     = (const float*)d_in[5];
    const float* inm     = (const float*)d_in[6];
    const float* oldact  = (const float*)d_in[7];
    const int*   rfstart = (const int*)d_in[8];
    float* out = (float*)d_out;
    float* ws  = (float*)d_ws;

    hipMemsetAsync(d_out, 0, sizeof(float) * CCH * XD * YD, stream);

    hipLaunchKernelGGL(k_aff_prep, dim3(AFF_BLOCKS + PREP_BLOCKS), dim3(256), 0, stream,
                       input, affw, affm, exw, exm, inw, inm, oldact, rfstart, ws);

    hipLaunchKernelGGL(k_lateral, dim3(24, 3, QSPLIT), dim3(256), 0, stream, ws, out);
}